// Round 6
// baseline (314.471 us; speedup 1.0000x reference)
//
#include <hip/hip_runtime.h>
#include <stdint.h>

#define N_NODES 50000
#define N_EDGES 800000
#define D_IN 128
#define H1 96
#define H1P 48   // packed bf16 pairs per node
#define H2 64
#define GEMM_NODES 32
#define SCAN_BLK 256
#define N_SBLK ((N_NODES + SCAN_BLK - 1) / SCAN_BLK)   // 196
#define AGG_GRID 2048

__device__ __forceinline__ uint16_t f2bf(float f) {
    uint32_t u = __float_as_uint(f);
    uint32_t r = (u + 0x7FFFu + ((u >> 16) & 1u)) >> 16;  // RTN-even
    return (uint16_t)r;
}
__device__ __forceinline__ float bf_lo(uint32_t v) { return __uint_as_float(v << 16); }
__device__ __forceinline__ float bf_hi(uint32_t v) { return __uint_as_float(v & 0xFFFF0000u); }

// ---------------- degree histogram ----------------
__global__ void count_deg_kernel(const int* __restrict__ dst, int* __restrict__ deg) {
    int i = blockIdx.x * blockDim.x + threadIdx.x;
    int stride = gridDim.x * blockDim.x;
    for (int e = i; e < N_EDGES; e += stride)
        atomicAdd(&deg[dst[e]], 1);
}

// ---------------- 3-phase device-wide exclusive scan ----------------
__global__ __launch_bounds__(SCAN_BLK) void deg_part_kernel(const int* __restrict__ deg,
                                                            int* __restrict__ block_sums) {
    __shared__ int s[SCAN_BLK];
    int t = threadIdx.x;
    int i = blockIdx.x * SCAN_BLK + t;
    s[t] = (i < N_NODES) ? deg[i] : 0;
    __syncthreads();
    for (int off = SCAN_BLK / 2; off > 0; off >>= 1) {
        if (t < off) s[t] += s[t + off];
        __syncthreads();
    }
    if (t == 0) block_sums[blockIdx.x] = s[0];
}

__global__ __launch_bounds__(SCAN_BLK) void block_scan_kernel(int* __restrict__ block_sums) {
    __shared__ int s[SCAN_BLK];
    int t = threadIdx.x;
    int v = (t < N_SBLK) ? block_sums[t] : 0;
    s[t] = v;
    __syncthreads();
    for (int off = 1; off < SCAN_BLK; off <<= 1) {
        int u = (t >= off) ? s[t - off] : 0;
        __syncthreads();
        s[t] += u;
        __syncthreads();
    }
    if (t < N_SBLK) block_sums[t] = s[t] - v;  // exclusive
}

__global__ __launch_bounds__(SCAN_BLK) void deg_scan_kernel(const int* __restrict__ deg,
                                                            const int* __restrict__ block_off,
                                                            int* __restrict__ row_start,
                                                            int* __restrict__ cursor,
                                                            float* __restrict__ dinv) {
    __shared__ int s[SCAN_BLK];
    int t = threadIdx.x;
    int i = blockIdx.x * SCAN_BLK + t;
    int v = (i < N_NODES) ? deg[i] : 0;
    s[t] = v;
    __syncthreads();
    for (int off = 1; off < SCAN_BLK; off <<= 1) {
        int u = (t >= off) ? s[t - off] : 0;
        __syncthreads();
        s[t] += u;
        __syncthreads();
    }
    int excl = s[t] - v + block_off[blockIdx.x];
    if (i < N_NODES) {
        row_start[i] = excl;
        cursor[i] = excl;
        dinv[i] = rsqrtf((float)v + 1.0f);  // +1 self-loop
    }
    if (i == 0) row_start[N_NODES] = N_EDGES;
}

// ---------------- scatter edges into CSR ----------------
__global__ void scatter_kernel(const int* __restrict__ src, const int* __restrict__ dst,
                               int* __restrict__ cursor, int* __restrict__ sorted_src) {
    int i = blockIdx.x * blockDim.x + threadIdx.x;
    int stride = gridDim.x * blockDim.x;
    for (int e = i; e < N_EDGES; e += stride) {
        int d = dst[e];
        int pos = atomicAdd(&cursor[d], 1);
        sorted_src[pos] = src[e];
    }
}

// ---------------- hs(bf16) = (x @ W1) * dinv[n] ----------------
__global__ __launch_bounds__(256) void gemm_kernel(const float* __restrict__ x,
                                                   const float* __restrict__ W1,
                                                   const float* __restrict__ dinv,
                                                   uint16_t* __restrict__ hs) {
    __shared__ float sW[D_IN * H1];          // 48 KB
    __shared__ float sx[GEMM_NODES * D_IN];  // 16 KB
    int tid = threadIdx.x;

    for (int i = tid; i < D_IN * H1 / 4; i += 256)
        ((float4*)sW)[i] = ((const float4*)W1)[i];

    int base = blockIdx.x * GEMM_NODES;
    const float4* x4 = (const float4*)x;
    for (int i = tid; i < GEMM_NODES * D_IN / 4; i += 256) {
        int n = base + i / (D_IN / 4);
        if (n < N_NODES) ((float4*)sx)[i] = x4[(size_t)base * (D_IN / 4) + i];
    }
    __syncthreads();

    int fg = tid & 31;
    int ng = tid >> 5;

    float acc[4][3];
#pragma unroll
    for (int i = 0; i < 4; ++i)
#pragma unroll
        for (int j = 0; j < 3; ++j) acc[i][j] = 0.0f;

#pragma unroll 4
    for (int k = 0; k < D_IN; ++k) {
        float w0 = sW[k * H1 + fg];
        float w1 = sW[k * H1 + fg + 32];
        float w2 = sW[k * H1 + fg + 64];
#pragma unroll
        for (int i = 0; i < 4; ++i) {
            float xv = sx[(ng * 4 + i) * D_IN + k];
            acc[i][0] = fmaf(xv, w0, acc[i][0]);
            acc[i][1] = fmaf(xv, w1, acc[i][1]);
            acc[i][2] = fmaf(xv, w2, acc[i][2]);
        }
    }

#pragma unroll
    for (int i = 0; i < 4; ++i) {
        int n = base + ng * 4 + i;
        if (n < N_NODES) {
            float dv = dinv[n];
            hs[(size_t)n * H1 + fg]      = f2bf(acc[i][0] * dv);
            hs[(size_t)n * H1 + fg + 32] = f2bf(acc[i][1] * dv);
            hs[(size_t)n * H1 + fg + 64] = f2bf(acc[i][2] * dv);
        }
    }
}

// ---------------- fused pull-aggregate + ReLU + sum-pool + MLP head ----------------
// One node at a time PER BLOCK: 4 waves split the node's edge list (serial chain
// cut 4x vs one-wave-per-node), lane j<48 owns packed features (2j,2j+1).
// Double-buffered LDS partials -> one barrier per node. Last block (ticket
// counter) runs the tiny 3-layer MLP inline.
__global__ __launch_bounds__(256) void agg_pool_kernel(const uint32_t* __restrict__ hs2,  // [N][48]
                                                       const int* __restrict__ row_start,
                                                       const int* __restrict__ sorted_src,
                                                       const float* __restrict__ dinv,
                                                       const float* __restrict__ b1,
                                                       float* __restrict__ g,
                                                       int* __restrict__ done,
                                                       const float* __restrict__ lw1, const float* __restrict__ lb1,
                                                       const float* __restrict__ lw2, const float* __restrict__ lb2,
                                                       const float* __restrict__ lw3, const float* __restrict__ lb3,
                                                       float* __restrict__ out) {
    __shared__ float part[2][4][H1];  // double-buffered per-wave partials (3 KB)
    int tid = threadIdx.x;
    int wave = tid >> 6;
    int j = tid & 63;
    bool act = j < H1P;
    float b0 = 0.0f, b1v = 0.0f;
    if (act) { b0 = b1[2 * j]; b1v = b1[2 * j + 1]; }
    float g0 = 0.0f, g1 = 0.0f;

    int p = 0;
    for (int n = blockIdx.x; n < N_NODES; n += gridDim.x) {
        int rs = row_start[n];
        int re = row_start[n + 1];
        int len = re - rs;
        float a0 = 0.0f, a1 = 0.0f;
        if (wave == 0 && act) {
            uint32_t v = hs2[n * H1P + j];  // self-loop term
            a0 = bf_lo(v); a1 = bf_hi(v);
        }
        int q = (len + 3) >> 2;
        int e = rs + wave * q;
        int ee = e + q;
        if (ee > re) ee = re;
        for (; e + 4 <= ee; e += 4) {
            int s0 = sorted_src[e];
            int s1 = sorted_src[e + 1];
            int s2 = sorted_src[e + 2];
            int s3 = sorted_src[e + 3];
            if (act) {
                uint32_t v0 = hs2[s0 * H1P + j];
                uint32_t v1 = hs2[s1 * H1P + j];
                uint32_t v2 = hs2[s2 * H1P + j];
                uint32_t v3 = hs2[s3 * H1P + j];
                a0 += (bf_lo(v0) + bf_lo(v1)) + (bf_lo(v2) + bf_lo(v3));
                a1 += (bf_hi(v0) + bf_hi(v1)) + (bf_hi(v2) + bf_hi(v3));
            }
        }
        for (; e < ee; ++e) {
            int s = sorted_src[e];
            if (act) { uint32_t v = hs2[s * H1P + j]; a0 += bf_lo(v); a1 += bf_hi(v); }
        }
        if (act) { part[p][wave][2 * j] = a0; part[p][wave][2 * j + 1] = a1; }
        __syncthreads();
        if (wave == 0 && act) {
            float s0 = (part[p][0][2 * j] + part[p][1][2 * j]) +
                       (part[p][2][2 * j] + part[p][3][2 * j]);
            float s1 = (part[p][0][2 * j + 1] + part[p][1][2 * j + 1]) +
                       (part[p][2][2 * j + 1] + part[p][3][2 * j + 1]);
            float dv = dinv[n];
            g0 += fmaxf(fmaf(dv, s0, b0), 0.0f);
            g1 += fmaxf(fmaf(dv, s1, b1v), 0.0f);
        }
        p ^= 1;  // double-buffer: wave0's read of buffer p is protected by the
                 // NEXT iteration's barrier before p is reused
    }

    if (wave == 0 && act) {
        atomicAdd(&g[2 * j], g0);
        atomicAdd(&g[2 * j + 1], g1);
    }
    __syncthreads();

    // ---- ticket: last block runs the MLP head ----
    __shared__ int is_last;
    if (tid == 0) {
        __threadfence();
        int old = atomicAdd(done, 1);
        is_last = (old == (int)gridDim.x - 1) ? 1 : 0;
        if (is_last) __threadfence();
    }
    __syncthreads();
    if (!is_last) return;

    __shared__ float sg[H1], v1[H1], v2[H2];
    if (tid < H1) sg[tid] = g[tid];
    __syncthreads();
    if (tid < H1) {
        float a = lb1[tid];
#pragma unroll 8
        for (int k = 0; k < H1; ++k) a = fmaf(sg[k], lw1[k * H1 + tid], a);
        v1[tid] = fmaxf(a, 0.0f);
    }
    __syncthreads();
    if (tid < H2) {
        float a = lb2[tid];
#pragma unroll 8
        for (int k = 0; k < H1; ++k) a = fmaf(v1[k], lw2[k * H2 + tid], a);
        v2[tid] = fmaxf(a, 0.0f);
    }
    __syncthreads();
    if (tid < 64) {
        float pr = v2[tid] * lw3[tid];
#pragma unroll
        for (int off = 32; off > 0; off >>= 1) pr += __shfl_down(pr, off, 64);
        if (tid == 0) out[0] = pr + lb3[0];
    }
}

extern "C" void kernel_launch(void* const* d_in, const int* in_sizes, int n_in,
                              void* d_out, int out_size, void* d_ws, size_t ws_size,
                              hipStream_t stream) {
    const float* x   = (const float*)d_in[0];
    const int*   ei  = (const int*)d_in[1];      // [2, N_EDGES] int32
    const float* W1  = (const float*)d_in[2];
    const float* b1  = (const float*)d_in[3];
    const float* lw1 = (const float*)d_in[4];
    const float* lb1 = (const float*)d_in[5];
    const float* lw2 = (const float*)d_in[6];
    const float* lb2 = (const float*)d_in[7];
    const float* lw3 = (const float*)d_in[8];
    const float* lb3 = (const float*)d_in[9];
    float* out = (float*)d_out;

    const int* src = ei;
    const int* dst = ei + N_EDGES;

    char* ws = (char*)d_ws;
    size_t off = 0;
    auto alloc = [&](size_t bytes) {
        char* p = ws + off;
        off = (off + bytes + 255) & ~(size_t)255;
        return p;
    };
    // deg, g, done contiguous so one memset clears all three
    int*      deg        = (int*)alloc((size_t)N_NODES * sizeof(int));
    float*    g          = (float*)alloc((size_t)H1 * sizeof(float));
    int*      done       = (int*)alloc(sizeof(int));
    float*    dinv       = (float*)alloc((size_t)N_NODES * sizeof(float));
    int*      row_start  = (int*)alloc((size_t)(N_NODES + 1) * sizeof(int));
    int*      cursor     = (int*)alloc((size_t)N_NODES * sizeof(int));
    int*      block_sums = (int*)alloc((size_t)N_SBLK * sizeof(int));
    int*      sorted_src = (int*)alloc((size_t)N_EDGES * sizeof(int));
    uint16_t* hs         = (uint16_t*)alloc((size_t)N_NODES * H1 * sizeof(uint16_t));
    (void)ws_size;

    hipMemsetAsync(deg, 0, (char*)(done + 1) - (char*)deg, stream);

    count_deg_kernel<<<2048, 256, 0, stream>>>(dst, deg);
    deg_part_kernel<<<N_SBLK, SCAN_BLK, 0, stream>>>(deg, block_sums);
    block_scan_kernel<<<1, SCAN_BLK, 0, stream>>>(block_sums);
    deg_scan_kernel<<<N_SBLK, SCAN_BLK, 0, stream>>>(deg, block_sums, row_start, cursor, dinv);
    scatter_kernel<<<2048, 256, 0, stream>>>(src, dst, cursor, sorted_src);

    gemm_kernel<<<(N_NODES + GEMM_NODES - 1) / GEMM_NODES, 256, 0, stream>>>(x, W1, dinv, hs);

    agg_pool_kernel<<<AGG_GRID, 256, 0, stream>>>((const uint32_t*)hs, row_start, sorted_src,
                                                  dinv, b1, g, done,
                                                  lw1, lb1, lw2, lb2, lw3, lb3, out);
}

// Round 7
// 248.340 us; speedup vs baseline: 1.2663x; 1.2663x over previous
//
#include <hip/hip_runtime.h>
#include <stdint.h>

#define N_NODES 50000
#define N_EDGES 800000
#define D_IN 128
#define H1 96
#define H2 64
#define GEMM_NODES 32
#define GEMM_BLOCKS ((N_NODES + GEMM_NODES - 1) / GEMM_NODES)  // 1563
#define COUNT_BLOCKS 256
#define SCAN_BLK 256
#define N_SBLK ((N_NODES + SCAN_BLK - 1) / SCAN_BLK)   // 196
#define SCAT_BLOCKS 2048
#define SCALE_BLOCKS 512

// =============== K1: gemm-h (x @ W1 -> h fp32)  ||  count_deg ===============
__global__ __launch_bounds__(256) void k1_gemm_count(const float* __restrict__ x,
                                                     const float* __restrict__ W1,
                                                     float* __restrict__ h,
                                                     const int* __restrict__ dst,
                                                     int* __restrict__ deg) {
    __shared__ float sW[D_IN * H1];          // 48 KB
    __shared__ float sx[GEMM_NODES * D_IN];  // 16 KB
    int tid = threadIdx.x;

    if (blockIdx.x < GEMM_BLOCKS) {
        // ---- GEMM arm ----
        for (int i = tid; i < D_IN * H1 / 4; i += 256)
            ((float4*)sW)[i] = ((const float4*)W1)[i];

        int base = blockIdx.x * GEMM_NODES;
        const float4* x4 = (const float4*)x;
        for (int i = tid; i < GEMM_NODES * D_IN / 4; i += 256) {
            int n = base + i / (D_IN / 4);
            if (n < N_NODES) ((float4*)sx)[i] = x4[(size_t)base * (D_IN / 4) + i];
        }
        __syncthreads();

        int fg = tid & 31;
        int ng = tid >> 5;

        float acc[4][3];
#pragma unroll
        for (int i = 0; i < 4; ++i)
#pragma unroll
            for (int j = 0; j < 3; ++j) acc[i][j] = 0.0f;

#pragma unroll 4
        for (int k = 0; k < D_IN; ++k) {
            float w0 = sW[k * H1 + fg];
            float w1 = sW[k * H1 + fg + 32];
            float w2 = sW[k * H1 + fg + 64];
#pragma unroll
            for (int i = 0; i < 4; ++i) {
                float xv = sx[(ng * 4 + i) * D_IN + k];
                acc[i][0] = fmaf(xv, w0, acc[i][0]);
                acc[i][1] = fmaf(xv, w1, acc[i][1]);
                acc[i][2] = fmaf(xv, w2, acc[i][2]);
            }
        }

#pragma unroll
        for (int i = 0; i < 4; ++i) {
            int n = base + ng * 4 + i;
            if (n < N_NODES) {
                h[(size_t)n * H1 + fg]      = acc[i][0];
                h[(size_t)n * H1 + fg + 32] = acc[i][1];
                h[(size_t)n * H1 + fg + 64] = acc[i][2];
            }
        }
    } else {
        // ---- count_deg arm: int4-vectorized dst stream, fire-and-forget atomics ----
        int bid = blockIdx.x - GEMM_BLOCKS;
        int gid = bid * 256 + tid;
        int stride = COUNT_BLOCKS * 256;
        const int4* d4 = (const int4*)dst;
        for (int i = gid; i < N_EDGES / 4; i += stride) {
            int4 d = d4[i];
            atomicAdd(&deg[d.x], 1);
            atomicAdd(&deg[d.y], 1);
            atomicAdd(&deg[d.z], 1);
            atomicAdd(&deg[d.w], 1);
        }
    }
}

// ---------------- 3-phase device-wide exclusive scan ----------------
__global__ __launch_bounds__(SCAN_BLK) void deg_part_kernel(const int* __restrict__ deg,
                                                            int* __restrict__ block_sums) {
    __shared__ int s[SCAN_BLK];
    int t = threadIdx.x;
    int i = blockIdx.x * SCAN_BLK + t;
    s[t] = (i < N_NODES) ? deg[i] : 0;
    __syncthreads();
    for (int off = SCAN_BLK / 2; off > 0; off >>= 1) {
        if (t < off) s[t] += s[t + off];
        __syncthreads();
    }
    if (t == 0) block_sums[blockIdx.x] = s[0];
}

__global__ __launch_bounds__(SCAN_BLK) void block_scan_kernel(int* __restrict__ block_sums) {
    __shared__ int s[SCAN_BLK];
    int t = threadIdx.x;
    int v = (t < N_SBLK) ? block_sums[t] : 0;
    s[t] = v;
    __syncthreads();
    for (int off = 1; off < SCAN_BLK; off <<= 1) {
        int u = (t >= off) ? s[t - off] : 0;
        __syncthreads();
        s[t] += u;
        __syncthreads();
    }
    if (t < N_SBLK) block_sums[t] = s[t] - v;  // exclusive
}

__global__ __launch_bounds__(SCAN_BLK) void deg_scan_kernel(const int* __restrict__ deg,
                                                            const int* __restrict__ block_off,
                                                            int* __restrict__ row_start,
                                                            int* __restrict__ cursor,
                                                            float* __restrict__ dinv) {
    __shared__ int s[SCAN_BLK];
    int t = threadIdx.x;
    int i = blockIdx.x * SCAN_BLK + t;
    int v = (i < N_NODES) ? deg[i] : 0;
    s[t] = v;
    __syncthreads();
    for (int off = 1; off < SCAN_BLK; off <<= 1) {
        int u = (t >= off) ? s[t - off] : 0;
        __syncthreads();
        s[t] += u;
        __syncthreads();
    }
    int excl = s[t] - v + block_off[blockIdx.x];
    if (i < N_NODES) {
        row_start[i] = excl;
        cursor[i] = excl;
        dinv[i] = rsqrtf((float)v + 1.0f);  // +1 self-loop
    }
    if (i == 0) row_start[N_NODES] = N_EDGES;
}

// =============== K3: scatter (CSR)  ||  hs = h * dinv[row] in-place ===============
__global__ __launch_bounds__(256) void k3_scatter_scale(const int* __restrict__ src,
                                                        const int* __restrict__ dst,
                                                        int* __restrict__ cursor,
                                                        int* __restrict__ sorted_src,
                                                        float* __restrict__ h,
                                                        const float* __restrict__ dinv) {
    int tid = threadIdx.x;
    if (blockIdx.x < SCAT_BLOCKS) {
        int gid = blockIdx.x * 256 + tid;
        int stride = SCAT_BLOCKS * 256;
        for (int e = gid; e < N_EDGES; e += stride) {
            int d = dst[e];
            int pos = atomicAdd(&cursor[d], 1);
            sorted_src[pos] = src[e];
        }
    } else {
        // scale arm: 50000*96 floats = 1.2M float4
        int bid = blockIdx.x - SCAT_BLOCKS;
        int gid = bid * 256 + tid;
        int stride = SCALE_BLOCKS * 256;
        float4* h4 = (float4*)h;
        const int TOT = N_NODES * (H1 / 4);  // 1,200,000
        for (int i = gid; i < TOT; i += stride) {
            int n = i / (H1 / 4);
            float dv = dinv[n];
            float4 v = h4[i];
            v.x *= dv; v.y *= dv; v.z *= dv; v.w *= dv;
            h4[i] = v;
        }
    }
}

// ---------------- fused pull-aggregate + ReLU + sum-pool (R3-exact, fp32) ----------------
__global__ __launch_bounds__(256) void agg_pool_kernel(const float* __restrict__ hs,
                                                       const int* __restrict__ row_start,
                                                       const int* __restrict__ sorted_src,
                                                       const float* __restrict__ dinv,
                                                       const float* __restrict__ b1,
                                                       float* __restrict__ g) {
    int tid = threadIdx.x;
    int grp = tid >> 7;
    int f = tid & 127;
    bool act = f < H1;
    float bf = act ? b1[f] : 0.0f;
    float gacc = 0.0f;

    for (int n = blockIdx.x * 2 + grp; n < N_NODES; n += gridDim.x * 2) {
        float acc = act ? hs[(size_t)n * H1 + f] : 0.0f;  // self-loop term
        int e = row_start[n];
        int eend = row_start[n + 1];
        for (; e + 4 <= eend; e += 4) {
            int s0 = sorted_src[e];
            int s1 = sorted_src[e + 1];
            int s2 = sorted_src[e + 2];
            int s3 = sorted_src[e + 3];
            if (act) {
                float v0 = hs[(size_t)s0 * H1 + f];
                float v1 = hs[(size_t)s1 * H1 + f];
                float v2 = hs[(size_t)s2 * H1 + f];
                float v3 = hs[(size_t)s3 * H1 + f];
                acc += (v0 + v1) + (v2 + v3);
            }
        }
        for (; e < eend; ++e) {
            int s = sorted_src[e];
            if (act) acc += hs[(size_t)s * H1 + f];
        }
        if (act) gacc += fmaxf(fmaf(dinv[n], acc, bf), 0.0f);
    }

    __shared__ float sg[H1];
    if (grp == 0 && act) sg[f] = gacc;
    __syncthreads();
    if (grp == 1 && act) atomicAdd(&sg[f], gacc);
    __syncthreads();
    if (grp == 0 && act) atomicAdd(&g[f], sg[f]);
}

// ---------------- tiny MLP head (weights staged in LDS) ----------------
__global__ __launch_bounds__(256) void mlp_kernel(const float* __restrict__ g,
                           const float* __restrict__ lw1, const float* __restrict__ lb1,
                           const float* __restrict__ lw2, const float* __restrict__ lb2,
                           const float* __restrict__ lw3, const float* __restrict__ lb3,
                           float* __restrict__ out) {
    __shared__ float slw1[H1 * H1];  // 36 KB
    __shared__ float slw2[H1 * H2];  // 24 KB
    __shared__ float slw3[H2];
    __shared__ float sg[H1], v1[H1], v2[H2];
    int t = threadIdx.x;  // 256 threads
    for (int i = t; i < H1 * H1 / 4; i += 256)
        ((float4*)slw1)[i] = ((const float4*)lw1)[i];
    for (int i = t; i < H1 * H2 / 4; i += 256)
        ((float4*)slw2)[i] = ((const float4*)lw2)[i];
    if (t < H2) slw3[t] = lw3[t];
    if (t < H1) sg[t] = g[t];
    __syncthreads();
    if (t < H1) {
        float a = lb1[t];
#pragma unroll 8
        for (int k = 0; k < H1; ++k) a = fmaf(sg[k], slw1[k * H1 + t], a);
        v1[t] = fmaxf(a, 0.0f);
    }
    __syncthreads();
    if (t < H2) {
        float a = lb2[t];
#pragma unroll 8
        for (int k = 0; k < H1; ++k) a = fmaf(v1[k], slw2[k * H2 + t], a);
        v2[t] = fmaxf(a, 0.0f);
    }
    __syncthreads();
    if (t == 0) {
        float a = lb3[0];
#pragma unroll 8
        for (int k = 0; k < H2; ++k) a = fmaf(v2[k], slw3[k], a);
        out[0] = a;
    }
}

extern "C" void kernel_launch(void* const* d_in, const int* in_sizes, int n_in,
                              void* d_out, int out_size, void* d_ws, size_t ws_size,
                              hipStream_t stream) {
    const float* x   = (const float*)d_in[0];
    const int*   ei  = (const int*)d_in[1];      // [2, N_EDGES] int32
    const float* W1  = (const float*)d_in[2];
    const float* b1  = (const float*)d_in[3];
    const float* lw1 = (const float*)d_in[4];
    const float* lb1 = (const float*)d_in[5];
    const float* lw2 = (const float*)d_in[6];
    const float* lb2 = (const float*)d_in[7];
    const float* lw3 = (const float*)d_in[8];
    const float* lb3 = (const float*)d_in[9];
    float* out = (float*)d_out;

    const int* src = ei;
    const int* dst = ei + N_EDGES;

    char* ws = (char*)d_ws;
    size_t off = 0;
    auto alloc = [&](size_t bytes) {
        char* p = ws + off;
        off = (off + bytes + 255) & ~(size_t)255;
        return p;
    };
    // deg and g contiguous so one memset clears both
    int*   deg        = (int*)alloc((size_t)N_NODES * sizeof(int));
    float* g          = (float*)alloc((size_t)H1 * sizeof(float));
    float* dinv       = (float*)alloc((size_t)N_NODES * sizeof(float));
    int*   row_start  = (int*)alloc((size_t)(N_NODES + 1) * sizeof(int));
    int*   cursor     = (int*)alloc((size_t)N_NODES * sizeof(int));
    int*   block_sums = (int*)alloc((size_t)N_SBLK * sizeof(int));
    int*   sorted_src = (int*)alloc((size_t)N_EDGES * sizeof(int));
    float* h          = (float*)alloc((size_t)N_NODES * H1 * sizeof(float));  // becomes hs in-place
    (void)ws_size;

    hipMemsetAsync(deg, 0, (char*)(g + H1) - (char*)deg, stream);

    // K1: gemm (h = x@W1)  ||  degree histogram
    k1_gemm_count<<<GEMM_BLOCKS + COUNT_BLOCKS, 256, 0, stream>>>(x, W1, h, dst, deg);

    deg_part_kernel<<<N_SBLK, SCAN_BLK, 0, stream>>>(deg, block_sums);
    block_scan_kernel<<<1, SCAN_BLK, 0, stream>>>(block_sums);
    deg_scan_kernel<<<N_SBLK, SCAN_BLK, 0, stream>>>(deg, block_sums, row_start, cursor, dinv);

    // K3: CSR scatter  ||  h *= dinv[row]
    k3_scatter_scale<<<SCAT_BLOCKS + SCALE_BLOCKS, 256, 0, stream>>>(src, dst, cursor, sorted_src, h, dinv);

    agg_pool_kernel<<<2048, 256, 0, stream>>>(h, row_start, sorted_src, dinv, b1, g);

    mlp_kernel<<<1, 256, 0, stream>>>(g, lw1, lb1, lw2, lb2, lw3, lb3, out);
}